// Round 18
// baseline (96.202 us; speedup 1.0000x reference)
//
#include <hip/hip_runtime.h>
#include <cmath>

#define T_DIM 2048
#define B_DIM 8
#define C_DIM 1024
#define H_DIM 8
#define R_DIM 128
#define BH_DIM 64          // B*H
#define COLS 8192          // BH*R
#define COL4 2048          // COLS/4
#define NCH 128            // scan chunks (LT=16)
#define LT 16              // T per chunk
__device__ __constant__ float INV_K = 0.33333333333333333f;

typedef _Float16 h4 __attribute__((ext_vector_type(4)));
typedef _Float16 h8 __attribute__((ext_vector_type(8)));
typedef float f4 __attribute__((ext_vector_type(4)));

// ---- Kernel A: offsets GEMM + chunk sums + LOCAL scan (ONE x read) ----
// 512-THREAD BLOCKS: one 64KB fp32 Wt staged per 8 waves. LDS 72KB -> 2
// blocks/CU = 16 waves/CU = 4 waves/SIMD (R10 form was grid-limited to 2).
// Sub 0/1 (256 thr each) own independent 16-t chunks (no handoff; fold is
// the full m=32..1 ladder). fp32 W path throughout -- R12-R15's fp16-Wt
// VALU explosion and launch_bounds VGPR-clamp spills both avoided.
__global__ __launch_bounds__(512, 2) void offcsum_kernel(
        const float4* __restrict__ x4, const float* __restrict__ W,
        const float* __restrict__ bias, float* __restrict__ off,
        float4* __restrict__ csum4, _Float16* __restrict__ Sloc) {
    __shared__ float Wt[16 * 1024];          // 64 KB
    __shared__ float sdata[2][4][4][64];     // 8 KB
    const int bid = blockIdx.x;
    const int cg  = bid >> 6;                // 0..7  == batch index b
    const int chp = bid & 63;                // chunk pair 0..63
    const int tid = threadIdx.x;             // 0..511
    const int sub = tid >> 8;                // 0/1: which 16-t chunk
    const int st  = tid & 255;               // sub-local thread
    const int wid = st >> 6, lane = st & 63;
    const int ch  = chp * 2 + sub;           // 0..127
    const int col4 = cg * 256 + st;          // global col4 in [0, 2048)

    const float4* xp = x4 + (size_t)(ch * LT) * COL4 + col4;
    // first group's x loads issued before LDS staging (longest latency)
    float4 xn0 = xp[0];
    float4 xn1 = xp[(size_t)1 * COL4];
    float4 xn2 = xp[(size_t)2 * COL4];
    float4 xn3 = xp[(size_t)3 * COL4];

    for (int idx = tid; idx < 4096; idx += 512) {
        int c = idx >> 2, j4 = (idx & 3) * 4;
        float4 w = *reinterpret_cast<const float4*>(W + c * 16 + j4);
        Wt[(j4 + 0) * 1024 + c] = w.x;
        Wt[(j4 + 1) * 1024 + c] = w.y;
        Wt[(j4 + 2) * 1024 + c] = w.z;
        Wt[(j4 + 3) * 1024 + c] = w.w;
    }
    __syncthreads();

    _Float16* Sp = Sloc + (size_t)(ch * LT) * COLS + col4 * 4;
    const int cbase = st * 4;
    float csx = 0.f, csy = 0.f, csz = 0.f, csw = 0.f;   // chunk sum
    float rx = 0.f, ry = 0.f, rz = 0.f, rw = 0.f;       // local running scan

#pragma unroll 1
    for (int g = 0; g < 4; ++g) {            // 4 groups x 4 t = 16 t
        float4 c0 = xn0, c1 = xn1, c2 = xn2, c3 = xn3;
        if (g < 3) {                          // prefetch next group
            const float4* np = xp + (size_t)((g + 1) * 4) * COL4;
            xn0 = np[0];
            xn1 = np[(size_t)1 * COL4];
            xn2 = np[(size_t)2 * COL4];
            xn3 = np[(size_t)3 * COL4];
        }
        float acc[64];
#pragma unroll
        for (int i = 0; i < 64; ++i) acc[i] = 0.f;
#pragma unroll
        for (int j = 0; j < 16; ++j) {
            float4 w = *reinterpret_cast<const float4*>(&Wt[j * 1024 + cbase]);
            acc[j]      = fmaf(c0.x, w.x, fmaf(c0.y, w.y, fmaf(c0.z, w.z, fmaf(c0.w, w.w, acc[j]))));
            acc[16 + j] = fmaf(c1.x, w.x, fmaf(c1.y, w.y, fmaf(c1.z, w.z, fmaf(c1.w, w.w, acc[16 + j]))));
            acc[32 + j] = fmaf(c2.x, w.x, fmaf(c2.y, w.y, fmaf(c2.z, w.z, fmaf(c2.w, w.w, acc[32 + j]))));
            acc[48 + j] = fmaf(c3.x, w.x, fmaf(c3.y, w.y, fmaf(c3.z, w.z, fmaf(c3.w, w.w, acc[48 + j]))));
        }
        csx += c0.x + c1.x + c2.x + c3.x;
        csy += c0.y + c1.y + c2.y + c3.y;
        csz += c0.z + c1.z + c2.z + c3.z;
        csw += c0.w + c1.w + c2.w + c3.w;
        // local scan: 4 rows, fp32 accum, fp16 store (8B/lane coalesced)
        {
            _Float16* sp = Sp + (size_t)(g * 4) * COLS;
            h4 o;
            rx = fmaf(c0.x, INV_K, rx); ry = fmaf(c0.y, INV_K, ry);
            rz = fmaf(c0.z, INV_K, rz); rw = fmaf(c0.w, INV_K, rw);
            o.x = (_Float16)rx; o.y = (_Float16)ry; o.z = (_Float16)rz; o.w = (_Float16)rw;
            *reinterpret_cast<h4*>(sp) = o;
            rx = fmaf(c1.x, INV_K, rx); ry = fmaf(c1.y, INV_K, ry);
            rz = fmaf(c1.z, INV_K, rz); rw = fmaf(c1.w, INV_K, rw);
            o.x = (_Float16)rx; o.y = (_Float16)ry; o.z = (_Float16)rz; o.w = (_Float16)rw;
            *reinterpret_cast<h4*>(sp + COLS) = o;
            rx = fmaf(c2.x, INV_K, rx); ry = fmaf(c2.y, INV_K, ry);
            rz = fmaf(c2.z, INV_K, rz); rw = fmaf(c2.w, INV_K, rw);
            o.x = (_Float16)rx; o.y = (_Float16)ry; o.z = (_Float16)rz; o.w = (_Float16)rw;
            *reinterpret_cast<h4*>(sp + 2 * COLS) = o;
            rx = fmaf(c3.x, INV_K, rx); ry = fmaf(c3.y, INV_K, ry);
            rz = fmaf(c3.z, INV_K, rz); rw = fmaf(c3.w, INV_K, rw);
            o.x = (_Float16)rx; o.y = (_Float16)ry; o.z = (_Float16)rz; o.w = (_Float16)rw;
            *reinterpret_cast<h4*>(sp + 3 * COLS) = o;
        }
        // value-folding wave reduction (full m=32..1): lane l ends with
        // value (tl<<4)|j summed across all 64 lanes.
#pragma unroll
        for (int m = 32; m >= 1; m >>= 1) {
            bool hi = (lane & m) != 0;
#pragma unroll
            for (int i = 0; i < m; ++i) {
                float send = hi ? acc[i] : acc[i + m];
                float recv = __shfl_xor(send, m, 64);
                acc[i] = (hi ? acc[i + m] : acc[i]) + recv;
            }
        }
        sdata[sub][wid][g][lane] = acc[0];
    }

    float4 agg; agg.x = csx * INV_K; agg.y = csy * INV_K; agg.z = csz * INV_K; agg.w = csw * INV_K;
    csum4[(size_t)ch * COL4 + col4] = agg;

    __syncthreads();
    // off write: per sub, 16 t x 16 j = 256 outputs = one per sub-thread
    {
        int g = st >> 6, l = st & 63;
        int tl = l >> 4, j = l & 15;
        float s = sdata[sub][0][g][l] + sdata[sub][1][g][l]
                + sdata[sub][2][g][l] + sdata[sub][3][g][l];
        s += bias[j];
        int t = ch * LT + g * 4 + tl;
        off[((size_t)t * B_DIM + cg) * 16 + j] = 1.f / (1.f + expf(-s));
    }
}

// ---- Kernel B: exclusive chunk-prefix of csum -> fp16 pfx (L2-resident) ----
__global__ void pfx_kernel(const float4* __restrict__ csum4, _Float16* __restrict__ pfxh) {
    int gid = blockIdx.x * 256 + threadIdx.x;   // NCH * COL4 threads
    int c = gid >> 11;                          // uniform within block
    int col4 = gid & (COL4 - 1);
    float rx = 0.f, ry = 0.f, rz = 0.f, rw = 0.f;
    for (int k = 0; k < c; ++k) {
        float4 v = csum4[(size_t)k * COL4 + col4];
        rx += v.x; ry += v.y; rz += v.z; rw += v.w;
    }
    h4 o; o.x = (_Float16)rx; o.y = (_Float16)ry; o.z = (_Float16)rz; o.w = (_Float16)rw;
    *reinterpret_cast<h4*>(pfxh + (size_t)c * COLS + col4 * 4) = o;
}

// ---- Kernel C: gather. S(i) = Sloc[i] + pfx[i>>4]; interp; diff. ----
__global__ void gather_kernel(const _Float16* __restrict__ Sloc,
                              const _Float16* __restrict__ pfxh,
                              const float* __restrict__ off,
                              float* __restrict__ out) {
    int bid = blockIdx.x;
    int sbid = (bid & 7) * 1024 + (bid >> 3);   // 8192 % 8 == 0 -> bijective
    int vid = sbid * 256 + threadIdx.x;         // T*B*C/8 vec elements
    int r8 = (vid & 15) << 3;
    int bh = (vid >> 4) & 63;
    int t = vid >> 10;
    int b = bh >> 3, h = bh & 7;
    const float* o = off + ((size_t)t * B_DIM + b) * 16;
    float aL = o[h], aR = o[8 + h];
    float tf = (float)t;
    float lenL = 1.f + aL * fmaxf(tf - 1.f, 0.f);
    float lenR = 1.f + aR * fmaxf((float)(T_DIM - 1) - tf - 1.f, 0.f);
    float fL = fmaxf(tf - lenL - 1.f, -1.f);
    float fR = fminf(tf + lenR, (float)(T_DIM - 1));
    int col = (bh << 7) | r8;

    float ffL = floorf(fL); int i0L = (int)ffL; float frL = fL - ffL;
    float ffR = floorf(fR); int i0R = (int)ffR; float frR = fR - ffR;
    int i0Lc = min(max(i0L, 0), T_DIM - 1), i1Lc = min(i0L + 1, T_DIM - 1);
    int i0Rc = min(max(i0R, 0), T_DIM - 1), i1Rc = min(i0R + 1, T_DIM - 1);

    const h8 zero8 = {0, 0, 0, 0, 0, 0, 0, 0};
    // row value = Sloc + chunk prefix (both fp16 streams, summed in fp32)
    h8 s1L = *reinterpret_cast<const h8*>(Sloc + (size_t)i1Lc * COLS + col);
    h8 p1L = *reinterpret_cast<const h8*>(pfxh + (size_t)(i1Lc >> 4) * COLS + col);
    h8 s1R = *reinterpret_cast<const h8*>(Sloc + (size_t)i1Rc * COLS + col);
    h8 p1R = *reinterpret_cast<const h8*>(pfxh + (size_t)(i1Rc >> 4) * COLS + col);
    h8 s0L = zero8, p0L = zero8, s0R = zero8, p0R = zero8;
    if (i0L >= 0) {
        s0L = *reinterpret_cast<const h8*>(Sloc + (size_t)i0Lc * COLS + col);
        p0L = *reinterpret_cast<const h8*>(pfxh + (size_t)(i0Lc >> 4) * COLS + col);
    }
    if (i0R >= 0) {
        s0R = *reinterpret_cast<const h8*>(Sloc + (size_t)i0Rc * COLS + col);
        p0R = *reinterpret_cast<const h8*>(pfxh + (size_t)(i0Rc >> 4) * COLS + col);
    }

    float res[8];
#pragma unroll
    for (int i = 0; i < 8; ++i) {
        float a0 = (float)s0R[i] + (float)p0R[i];
        float a1 = (float)s1R[i] + (float)p1R[i];
        float b0 = (float)s0L[i] + (float)p0L[i];
        float b1 = (float)s1L[i] + (float)p1L[i];
        res[i] = fmaf(frR, a1 - a0, a0) - fmaf(frL, b1 - b0, b0);
    }
    float* op = out + (size_t)vid * 8;
    f4 lo = {res[0], res[1], res[2], res[3]};
    f4 hi = {res[4], res[5], res[6], res[7]};
    __builtin_nontemporal_store(lo, reinterpret_cast<f4*>(op));
    __builtin_nontemporal_store(hi, reinterpret_cast<f4*>(op + 4));
}

extern "C" void kernel_launch(void* const* d_in, const int* in_sizes, int n_in,
                              void* d_out, int out_size, void* d_ws, size_t ws_size,
                              hipStream_t stream) {
    const float4* x4 = (const float4*)d_in[0];
    const float* W  = (const float*)d_in[1];
    const float* bi = (const float*)d_in[2];

    char* ws = (char*)d_ws;
    const size_t S_bytes    = (size_t)T_DIM * COLS * sizeof(_Float16);    // 32 MB
    const size_t off_bytes  = (size_t)T_DIM * B_DIM * 16 * sizeof(float); // 1 MB
    const size_t csum_bytes = (size_t)NCH * COL4 * sizeof(float4);        // 4 MB
    _Float16* Sloc = (_Float16*)ws;
    float* off     = (float*)(ws + S_bytes);
    float* csum    = (float*)(ws + S_bytes + off_bytes);
    _Float16* pfxh = (_Float16*)(ws + S_bytes + off_bytes + csum_bytes);  // 2 MB

    offcsum_kernel<<<512, 512, 0, stream>>>(x4, W, bi, off, (float4*)csum, Sloc);
    pfx_kernel<<<(NCH * COL4) / 256, 256, 0, stream>>>((const float4*)csum, pfxh);
    gather_kernel<<<(T_DIM * B_DIM * C_DIM / 8) / 256, 256, 0, stream>>>(
        Sloc, pfxh, off, (float*)d_out);
}

// Round 19
// 74.265 us; speedup vs baseline: 1.2954x; 1.2954x over previous
//
#include <hip/hip_runtime.h>
#include <cmath>

#define T_DIM 2048
#define B_DIM 8
#define C_DIM 1024
#define H_DIM 8
#define R_DIM 128
#define BH_DIM 64          // B*H
#define COLS 8192          // BH*R
#define COL4 2048          // COLS/4
#define NCH 64             // scan chunks
#define LT 32              // T per chunk
__device__ __constant__ float INV_K = 0.33333333333333333f;

typedef _Float16 h4 __attribute__((ext_vector_type(4)));
typedef _Float16 h8 __attribute__((ext_vector_type(8)));
typedef float f4 __attribute__((ext_vector_type(4)));

// ---- Kernel A: offsets GEMM + chunk sums + LOCAL scan (ONE x read) ----
// PROVEN best (R17, 74.5us total). Wt fp32 LDS + ds_read_b128; acc[64];
// depth-1 register prefetch; launch_bounds(256,2).
// DEAD ENDS (do not revisit): fp16-Wt (R12/R14/R15: VALU explosion, 180-308us
// even spill-free); launch_bounds(256,4) (VGPR clamp to 64 + scratch spill);
// W-in-registers (neutral); 512-thr shared-Wt blocks (R18: 96us).
__global__ __launch_bounds__(256, 2) void offcsum_kernel(
        const float4* __restrict__ x4, const float* __restrict__ W,
        const float* __restrict__ bias, float* __restrict__ off,
        float4* __restrict__ csum4, _Float16* __restrict__ Sloc) {
    __shared__ float Wt[16 * 1024];          // 64 KB
    __shared__ float sdata[4][8][64];        // 8 KB
    const int bid = blockIdx.x;
    const int cg = bid >> 6;                 // 0..7  == batch index b
    const int ch = bid & 63;                 // 0..63 == t chunk
    const int tid = threadIdx.x;
    const int wave = tid >> 6, lane = tid & 63;
    const int col4 = cg * 256 + tid;         // global col4 in [0, 2048)

    const float4* xp = x4 + (size_t)(ch * LT) * COL4 + col4;
    // first group's x loads issued first (longest latency)
    float4 xn0 = xp[0];
    float4 xn1 = xp[(size_t)1 * COL4];
    float4 xn2 = xp[(size_t)2 * COL4];
    float4 xn3 = xp[(size_t)3 * COL4];

    for (int idx = tid; idx < 4096; idx += 256) {
        int c = idx >> 2, j4 = (idx & 3) * 4;
        float4 w = *reinterpret_cast<const float4*>(W + c * 16 + j4);
        Wt[(j4 + 0) * 1024 + c] = w.x;
        Wt[(j4 + 1) * 1024 + c] = w.y;
        Wt[(j4 + 2) * 1024 + c] = w.z;
        Wt[(j4 + 3) * 1024 + c] = w.w;
    }
    __syncthreads();

    _Float16* Sp = Sloc + (size_t)(ch * LT) * COLS + col4 * 4;
    const int cbase = tid * 4;
    float csx = 0.f, csy = 0.f, csz = 0.f, csw = 0.f;   // chunk sum
    float rx = 0.f, ry = 0.f, rz = 0.f, rw = 0.f;       // local running scan

#pragma unroll 1
    for (int g = 0; g < 8; ++g) {
        float4 c0 = xn0, c1 = xn1, c2 = xn2, c3 = xn3;
        if (g < 7) {                          // prefetch next group
            const float4* np = xp + (size_t)((g + 1) * 4) * COL4;
            xn0 = np[0];
            xn1 = np[(size_t)1 * COL4];
            xn2 = np[(size_t)2 * COL4];
            xn3 = np[(size_t)3 * COL4];
        }
        float acc[64];
#pragma unroll
        for (int i = 0; i < 64; ++i) acc[i] = 0.f;
#pragma unroll
        for (int j = 0; j < 16; ++j) {
            float4 w = *reinterpret_cast<const float4*>(&Wt[j * 1024 + cbase]);
            acc[j]      = fmaf(c0.x, w.x, fmaf(c0.y, w.y, fmaf(c0.z, w.z, fmaf(c0.w, w.w, acc[j]))));
            acc[16 + j] = fmaf(c1.x, w.x, fmaf(c1.y, w.y, fmaf(c1.z, w.z, fmaf(c1.w, w.w, acc[16 + j]))));
            acc[32 + j] = fmaf(c2.x, w.x, fmaf(c2.y, w.y, fmaf(c2.z, w.z, fmaf(c2.w, w.w, acc[32 + j]))));
            acc[48 + j] = fmaf(c3.x, w.x, fmaf(c3.y, w.y, fmaf(c3.z, w.z, fmaf(c3.w, w.w, acc[48 + j]))));
        }
        csx += c0.x + c1.x + c2.x + c3.x;
        csy += c0.y + c1.y + c2.y + c3.y;
        csz += c0.z + c1.z + c2.z + c3.z;
        csw += c0.w + c1.w + c2.w + c3.w;
        // local scan: 4 rows, fp32 accum, fp16 store (8B/lane coalesced)
        {
            _Float16* sp = Sp + (size_t)(g * 4) * COLS;
            h4 o;
            rx = fmaf(c0.x, INV_K, rx); ry = fmaf(c0.y, INV_K, ry);
            rz = fmaf(c0.z, INV_K, rz); rw = fmaf(c0.w, INV_K, rw);
            o.x = (_Float16)rx; o.y = (_Float16)ry; o.z = (_Float16)rz; o.w = (_Float16)rw;
            *reinterpret_cast<h4*>(sp) = o;
            rx = fmaf(c1.x, INV_K, rx); ry = fmaf(c1.y, INV_K, ry);
            rz = fmaf(c1.z, INV_K, rz); rw = fmaf(c1.w, INV_K, rw);
            o.x = (_Float16)rx; o.y = (_Float16)ry; o.z = (_Float16)rz; o.w = (_Float16)rw;
            *reinterpret_cast<h4*>(sp + COLS) = o;
            rx = fmaf(c2.x, INV_K, rx); ry = fmaf(c2.y, INV_K, ry);
            rz = fmaf(c2.z, INV_K, rz); rw = fmaf(c2.w, INV_K, rw);
            o.x = (_Float16)rx; o.y = (_Float16)ry; o.z = (_Float16)rz; o.w = (_Float16)rw;
            *reinterpret_cast<h4*>(sp + 2 * COLS) = o;
            rx = fmaf(c3.x, INV_K, rx); ry = fmaf(c3.y, INV_K, ry);
            rz = fmaf(c3.z, INV_K, rz); rw = fmaf(c3.w, INV_K, rw);
            o.x = (_Float16)rx; o.y = (_Float16)ry; o.z = (_Float16)rz; o.w = (_Float16)rw;
            *reinterpret_cast<h4*>(sp + 3 * COLS) = o;
        }
        // value-folding wave reduction: lane l ends with value (tl<<4)|j
#pragma unroll
        for (int m = 32; m >= 1; m >>= 1) {
            bool hi = (lane & m) != 0;
#pragma unroll
            for (int i = 0; i < m; ++i) {
                float send = hi ? acc[i] : acc[i + m];
                float recv = __shfl_xor(send, m, 64);
                acc[i] = (hi ? acc[i + m] : acc[i]) + recv;
            }
        }
        sdata[wave][g][lane] = acc[0];
    }

    float4 agg; agg.x = csx * INV_K; agg.y = csy * INV_K; agg.z = csz * INV_K; agg.w = csw * INV_K;
    csum4[(size_t)ch * COL4 + col4] = agg;

    __syncthreads();
#pragma unroll
    for (int i = 0; i < 2; ++i) {
        int idx = tid + i * 256;
        int g = idx >> 6, l = idx & 63;
        int tl = l >> 4, j = l & 15;
        float s = sdata[0][g][l] + sdata[1][g][l] + sdata[2][g][l] + sdata[3][g][l];
        s += bias[j];
        int t = ch * LT + g * 4 + tl;
        off[((size_t)t * B_DIM + cg) * 16 + j] = 1.f / (1.f + expf(-s));
    }
}

// ---- Kernel B: exclusive chunk-prefix of csum -> fp16 pfx (L2-resident) ----
__global__ void pfx_kernel(const float4* __restrict__ csum4, _Float16* __restrict__ pfxh) {
    int gid = blockIdx.x * 256 + threadIdx.x;   // NCH * COL4 threads
    int c = gid >> 11;                          // uniform within block
    int col4 = gid & (COL4 - 1);
    float rx = 0.f, ry = 0.f, rz = 0.f, rw = 0.f;
    for (int k = 0; k < c; ++k) {
        float4 v = csum4[(size_t)k * COL4 + col4];
        rx += v.x; ry += v.y; rz += v.z; rw += v.w;
    }
    h4 o; o.x = (_Float16)rx; o.y = (_Float16)ry; o.z = (_Float16)rz; o.w = (_Float16)rw;
    *reinterpret_cast<h4*>(pfxh + (size_t)c * COLS + col4 * 4) = o;
}

// ---- Kernel C: gather. S(i) = Sloc[i] + pfx[i>>5]; interp; diff. ----
__global__ void gather_kernel(const _Float16* __restrict__ Sloc,
                              const _Float16* __restrict__ pfxh,
                              const float* __restrict__ off,
                              float* __restrict__ out) {
    int bid = blockIdx.x;
    int sbid = (bid & 7) * 1024 + (bid >> 3);   // 8192 % 8 == 0 -> bijective
    int vid = sbid * 256 + threadIdx.x;         // T*B*C/8 vec elements
    int r8 = (vid & 15) << 3;
    int bh = (vid >> 4) & 63;
    int t = vid >> 10;
    int b = bh >> 3, h = bh & 7;
    const float* o = off + ((size_t)t * B_DIM + b) * 16;
    float aL = o[h], aR = o[8 + h];
    float tf = (float)t;
    float lenL = 1.f + aL * fmaxf(tf - 1.f, 0.f);
    float lenR = 1.f + aR * fmaxf((float)(T_DIM - 1) - tf - 1.f, 0.f);
    float fL = fmaxf(tf - lenL - 1.f, -1.f);
    float fR = fminf(tf + lenR, (float)(T_DIM - 1));
    int col = (bh << 7) | r8;

    float ffL = floorf(fL); int i0L = (int)ffL; float frL = fL - ffL;
    float ffR = floorf(fR); int i0R = (int)ffR; float frR = fR - ffR;
    int i0Lc = min(max(i0L, 0), T_DIM - 1), i1Lc = min(i0L + 1, T_DIM - 1);
    int i0Rc = min(max(i0R, 0), T_DIM - 1), i1Rc = min(i0R + 1, T_DIM - 1);

    const h8 zero8 = {0, 0, 0, 0, 0, 0, 0, 0};
    // row value = Sloc + chunk prefix (both fp16 streams, summed in fp32)
    h8 s1L = *reinterpret_cast<const h8*>(Sloc + (size_t)i1Lc * COLS + col);
    h8 p1L = *reinterpret_cast<const h8*>(pfxh + (size_t)(i1Lc >> 5) * COLS + col);
    h8 s1R = *reinterpret_cast<const h8*>(Sloc + (size_t)i1Rc * COLS + col);
    h8 p1R = *reinterpret_cast<const h8*>(pfxh + (size_t)(i1Rc >> 5) * COLS + col);
    h8 s0L = zero8, p0L = zero8, s0R = zero8, p0R = zero8;
    if (i0L >= 0) {
        s0L = *reinterpret_cast<const h8*>(Sloc + (size_t)i0Lc * COLS + col);
        p0L = *reinterpret_cast<const h8*>(pfxh + (size_t)(i0Lc >> 5) * COLS + col);
    }
    if (i0R >= 0) {
        s0R = *reinterpret_cast<const h8*>(Sloc + (size_t)i0Rc * COLS + col);
        p0R = *reinterpret_cast<const h8*>(pfxh + (size_t)(i0Rc >> 5) * COLS + col);
    }

    float res[8];
#pragma unroll
    for (int i = 0; i < 8; ++i) {
        float a0 = (float)s0R[i] + (float)p0R[i];
        float a1 = (float)s1R[i] + (float)p1R[i];
        float b0 = (float)s0L[i] + (float)p0L[i];
        float b1 = (float)s1L[i] + (float)p1L[i];
        res[i] = fmaf(frR, a1 - a0, a0) - fmaf(frL, b1 - b0, b0);
    }
    float* op = out + (size_t)vid * 8;
    f4 lo = {res[0], res[1], res[2], res[3]};
    f4 hi = {res[4], res[5], res[6], res[7]};
    __builtin_nontemporal_store(lo, reinterpret_cast<f4*>(op));
    __builtin_nontemporal_store(hi, reinterpret_cast<f4*>(op + 4));
}

extern "C" void kernel_launch(void* const* d_in, const int* in_sizes, int n_in,
                              void* d_out, int out_size, void* d_ws, size_t ws_size,
                              hipStream_t stream) {
    const float4* x4 = (const float4*)d_in[0];
    const float* W  = (const float*)d_in[1];
    const float* bi = (const float*)d_in[2];

    char* ws = (char*)d_ws;
    const size_t S_bytes    = (size_t)T_DIM * COLS * sizeof(_Float16);    // 32 MB
    const size_t off_bytes  = (size_t)T_DIM * B_DIM * 16 * sizeof(float); // 1 MB
    const size_t csum_bytes = (size_t)NCH * COL4 * sizeof(float4);        // 2 MB
    _Float16* Sloc = (_Float16*)ws;
    float* off     = (float*)(ws + S_bytes);
    float* csum    = (float*)(ws + S_bytes + off_bytes);
    _Float16* pfxh = (_Float16*)(ws + S_bytes + off_bytes + csum_bytes);  // 1 MB

    offcsum_kernel<<<512, 256, 0, stream>>>(x4, W, bi, off, (float4*)csum, Sloc);
    pfx_kernel<<<(NCH * COL4) / 256, 256, 0, stream>>>((const float4*)csum, pfxh);
    gather_kernel<<<(T_DIM * B_DIM * C_DIM / 8) / 256, 256, 0, stream>>>(
        Sloc, pfxh, off, (float*)d_out);
}